// Round 7
// baseline (510.878 us; speedup 1.0000x reference)
//
#include <hip/hip_runtime.h>
#include <math.h>

#define HEADS 4
#define HID 64
#define HC 256
#define NEG_SLOPE 0.2f
#define GG 128

typedef __attribute__((ext_vector_type(8))) short short8;
typedef __attribute__((ext_vector_type(4))) float floatx4;
typedef unsigned short ush;

__device__ __forceinline__ ush f2bf(float f) {
  unsigned u = __float_as_uint(f);
  unsigned r = (u + 0x7FFFu + ((u >> 16) & 1u)) >> 16;  // RNE
  return (ush)r;
}
__device__ __forceinline__ float bf2f(ush h) {
  return __uint_as_float(((unsigned)h) << 16);
}

// ---------------- CSR build (counting sort by dst) ----------------
// counts must be zeroed (hipMemsetAsync); includes self-loops (i >= E).
__global__ void hist_kernel(const int* __restrict__ ei, int* counts, int E, int n) {
  int i = blockIdx.x * 256 + threadIdx.x;
  if (i >= E + n) return;
  int d = (i < E) ? ei[E + i] : (i - E);
  atomicAdd(&counts[d], 1);
}

__global__ __launch_bounds__(256) void scan_pass1(const int* __restrict__ counts,
                                                  int* __restrict__ bsums, int n) {
  int t = threadIdx.x;
  int i0 = blockIdx.x * 1024 + t * 4;
  int s = 0;
  if (i0 + 3 < n) {
    int4 v = *(const int4*)&counts[i0];
    s = v.x + v.y + v.z + v.w;
  } else {
#pragma unroll
    for (int k = 0; k < 4; ++k)
      if (i0 + k < n) s += counts[i0 + k];
  }
#pragma unroll
  for (int o = 1; o < 64; o <<= 1) s += __shfl_xor(s, o, 64);
  __shared__ int ws[4];
  if ((t & 63) == 0) ws[t >> 6] = s;
  __syncthreads();
  if (t == 0) bsums[blockIdx.x] = ws[0] + ws[1] + ws[2] + ws[3];
}

__global__ __launch_bounds__(256) void scan_pass2(int* __restrict__ bsums,
                                                  int* __restrict__ row_ptr, int nb, int n) {
  __shared__ int sh[256];
  int t = threadIdx.x;
  int v = (t < nb) ? bsums[t] : 0;
  sh[t] = v;
  __syncthreads();
  for (int off = 1; off < 256; off <<= 1) {
    int u = (t >= off) ? sh[t - off] : 0;
    __syncthreads();
    sh[t] += u;
    __syncthreads();
  }
  if (t < nb) bsums[t] = sh[t] - v;  // exclusive
  if (t == 255) row_ptr[n] = sh[255];
}

__global__ __launch_bounds__(256) void scan_pass3(const int* __restrict__ counts,
                                                  const int* __restrict__ bsums,
                                                  int* __restrict__ row_ptr,
                                                  int* __restrict__ cursor, int n) {
  int t = threadIdx.x;
  int i0 = blockIdx.x * 1024 + t * 4;
  int c0 = 0, c1 = 0, c2 = 0, c3 = 0;
  bool full = (i0 + 3 < n);
  if (full) {
    int4 v = *(const int4*)&counts[i0];
    c0 = v.x; c1 = v.y; c2 = v.z; c3 = v.w;
  } else {
    if (i0 + 0 < n) c0 = counts[i0 + 0];
    if (i0 + 1 < n) c1 = counts[i0 + 1];
    if (i0 + 2 < n) c2 = counts[i0 + 2];
    if (i0 + 3 < n) c3 = counts[i0 + 3];
  }
  int ts = c0 + c1 + c2 + c3;
  __shared__ int sh[256];
  sh[t] = ts;
  __syncthreads();
  for (int off = 1; off < 256; off <<= 1) {
    int u = (t >= off) ? sh[t - off] : 0;
    __syncthreads();
    sh[t] += u;
    __syncthreads();
  }
  int run = bsums[blockIdx.x] + sh[t] - ts;
  int r0 = run, r1 = run + c0, r2 = r1 + c1, r3 = r2 + c2;
  if (full) {
    *(int4*)&row_ptr[i0] = make_int4(r0, r1, r2, r3);
    *(int4*)&cursor[i0] = make_int4(r0, r1, r2, r3);
  } else {
    if (i0 + 0 < n) { row_ptr[i0 + 0] = r0; cursor[i0 + 0] = r0; }
    if (i0 + 1 < n) { row_ptr[i0 + 1] = r1; cursor[i0 + 1] = r1; }
    if (i0 + 2 < n) { row_ptr[i0 + 2] = r2; cursor[i0 + 2] = r2; }
    if (i0 + 3 < n) { row_ptr[i0 + 3] = r3; cursor[i0 + 3] = r3; }
  }
}

__global__ void scatter_kernel(const int* __restrict__ ei, int* cursor, int* srcs, int E, int n) {
  int i = blockIdx.x * 256 + threadIdx.x;
  if (i >= E + n) return;
  int s, d;
  if (i < E) { s = ei[i]; d = ei[E + i]; }
  else       { s = i - E; d = s; }
  int pos = atomicAdd(&cursor[d], 1);
  srcs[pos] = s;
}

// ---------------- fp32 -> bf16 hi/lo split (elementwise) ----------------
__global__ __launch_bounds__(256) void splitA_kernel(const float* __restrict__ A,
                                                     ush* __restrict__ Ah,
                                                     ush* __restrict__ Al, int total) {
  int i0 = (blockIdx.x * 256 + threadIdx.x) * 4;
  if (i0 + 3 < total) {
    float4 v = *(const float4*)&A[i0];
    ushort4 h = make_ushort4(f2bf(v.x), f2bf(v.y), f2bf(v.z), f2bf(v.w));
    ushort4 l = make_ushort4(f2bf(v.x - bf2f(h.x)), f2bf(v.y - bf2f(h.y)),
                             f2bf(v.z - bf2f(h.z)), f2bf(v.w - bf2f(h.w)));
    *(ushort4*)&Ah[i0] = h;
    *(ushort4*)&Al[i0] = l;
  } else {
    for (int k = 0; k < 4 && i0 + k < total; ++k) {
      float v = A[i0 + k];
      ush h = f2bf(v);
      Ah[i0 + k] = h;
      Al[i0 + k] = f2bf(v - bf2f(h));
    }
  }
}

// ---------------- both B matrices: fp32 [256,256] -> bf16 hi/lo TRANSPOSED [n][k] ----------------
__global__ void convertB_kernel(const float* __restrict__ W1, const float* __restrict__ W2,
                                ush* __restrict__ Bth1, ush* __restrict__ Btl1,
                                ush* __restrict__ Bth2, ush* __restrict__ Btl2) {
  int k = blockIdx.x, n = threadIdx.x;
  const float* B = blockIdx.y ? W2 : W1;
  ush* th = blockIdx.y ? Bth2 : Bth1;
  ush* tl = blockIdx.y ? Btl2 : Btl1;
  float v = B[k * HC + n];
  ush h = f2bf(v);
  ush l = f2bf(v - bf2f(h));
  th[n * HC + k] = h;
  tl[n * HC + k] = l;
}

// ---------------- bf16-split MFMA GEMM, full-N block (128x256) + fused att + bf16 C ----------------
// grid: ceil(M/128) blocks; 4 waves of 64x128 (2x2); A rows read exactly once.
#define LDA 40  // padded k-stride in shorts (80B)
__global__ __launch_bounds__(256) void gemm_kernel(
    const ush* __restrict__ Ah, const ush* __restrict__ Al,
    const ush* __restrict__ Bth, const ush* __restrict__ Btl,
    const float* __restrict__ att_src, const float* __restrict__ att_dst,
    ush* __restrict__ Cb, float* __restrict__ asrc_o, float* __restrict__ adst_o, int M) {
  __shared__ ush sAh[128 * LDA];
  __shared__ ush sAl[128 * LDA];
  __shared__ ush sBh[256 * LDA];
  __shared__ ush sBl[256 * LDA];

  int t = threadIdx.x;
  int lane = t & 63, wave = t >> 6;
  int wm = wave >> 1, wn = wave & 1;  // wave tile: rows wm*64.., cols wn*128..
  int q = lane >> 4, mrow = lane & 15;
  int r0 = blockIdx.x * 128;
  const int4 zero4 = make_int4(0, 0, 0, 0);

  floatx4 acc[4][8];
#pragma unroll
  for (int i = 0; i < 4; ++i)
#pragma unroll
    for (int j = 0; j < 8; ++j) acc[i][j] = (floatx4)(0.0f);

  // A staging tasks: 512 (row,seg8) per array -> t, t+256
  int ar0 = t >> 2, as0 = t & 3;
  int ar1 = (t + 256) >> 2, as1 = (t + 256) & 3;
  bool av0 = (r0 + ar0) < M, av1 = (r0 + ar1) < M;

  for (int k0 = 0; k0 < HC; k0 += 32) {
    __syncthreads();
    {
      size_t g0 = (size_t)(r0 + ar0) * HC + k0 + as0 * 8;
      size_t g1 = (size_t)(r0 + ar1) * HC + k0 + as1 * 8;
      *(int4*)&sAh[ar0 * LDA + as0 * 8] = av0 ? *(const int4*)&Ah[g0] : zero4;
      *(int4*)&sAh[ar1 * LDA + as1 * 8] = av1 ? *(const int4*)&Ah[g1] : zero4;
      *(int4*)&sAl[ar0 * LDA + as0 * 8] = av0 ? *(const int4*)&Al[g0] : zero4;
      *(int4*)&sAl[ar1 * LDA + as1 * 8] = av1 ? *(const int4*)&Al[g1] : zero4;
#pragma unroll
      for (int tau = 0; tau < 1024; tau += 256) {
        int br = (t + tau) >> 2, bs = (t + tau) & 3;
        size_t gb = (size_t)br * HC + k0 + bs * 8;
        *(int4*)&sBh[br * LDA + bs * 8] = *(const int4*)&Bth[gb];
        *(int4*)&sBl[br * LDA + bs * 8] = *(const int4*)&Btl[gb];
      }
    }
    __syncthreads();

    short8 ah[4], al[4];
#pragma unroll
    for (int i = 0; i < 4; ++i) {
      int ar = (wm * 64 + i * 16 + mrow) * LDA + q * 8;
      ah[i] = *(short8*)&sAh[ar];
      al[i] = *(short8*)&sAl[ar];
    }
#pragma unroll
    for (int j = 0; j < 8; ++j) {
      int br = (wn * 128 + j * 16 + mrow) * LDA + q * 8;
      short8 bh = *(short8*)&sBh[br];
      short8 bl = *(short8*)&sBl[br];
#pragma unroll
      for (int i = 0; i < 4; ++i) {
        acc[i][j] = __builtin_amdgcn_mfma_f32_16x16x32_bf16(ah[i], bh, acc[i][j], 0, 0, 0);
        acc[i][j] = __builtin_amdgcn_mfma_f32_16x16x32_bf16(ah[i], bl, acc[i][j], 0, 0, 0);
        acc[i][j] = __builtin_amdgcn_mfma_f32_16x16x32_bf16(al[i], bh, acc[i][j], 0, 0, 0);
      }
    }
  }

  // ---- fused att: wave wn owns heads wn*2 and wn*2+1 ----
#pragma unroll
  for (int jh = 0; jh < 2; ++jh) {
    int hd = wn * 2 + jh;
    float aS[4], aD[4];
#pragma unroll
    for (int jj = 0; jj < 4; ++jj) {
      aS[jj] = att_src[hd * 64 + jj * 16 + mrow];
      aD[jj] = att_dst[hd * 64 + jj * 16 + mrow];
    }
#pragma unroll
    for (int i = 0; i < 4; ++i) {
#pragma unroll
      for (int r = 0; r < 4; ++r) {
        float ps = acc[i][jh * 4 + 0][r] * aS[0] + acc[i][jh * 4 + 1][r] * aS[1] +
                   acc[i][jh * 4 + 2][r] * aS[2] + acc[i][jh * 4 + 3][r] * aS[3];
        float pd = acc[i][jh * 4 + 0][r] * aD[0] + acc[i][jh * 4 + 1][r] * aD[1] +
                   acc[i][jh * 4 + 2][r] * aD[2] + acc[i][jh * 4 + 3][r] * aD[3];
#pragma unroll
        for (int o = 1; o < 16; o <<= 1) {
          ps += __shfl_xor(ps, o, 64);
          pd += __shfl_xor(pd, o, 64);
        }
        int grow = r0 + wm * 64 + i * 16 + q * 4 + r;
        if (mrow == 0 && grow < M) {
          asrc_o[grow * HEADS + hd] = ps;
          adst_o[grow * HEADS + hd] = pd;
        }
      }
    }
  }

  // ---- bf16 C store (C/D layout: col=lane&15, row=(lane>>4)*4+reg) ----
#pragma unroll
  for (int i = 0; i < 4; ++i) {
#pragma unroll
    for (int j = 0; j < 8; ++j) {
      int col = wn * 128 + j * 16 + mrow;
#pragma unroll
      for (int r = 0; r < 4; ++r) {
        int grow = r0 + wm * 64 + i * 16 + q * 4 + r;
        if (grow < M) Cb[(size_t)grow * HC + col] = f2bf(acc[i][j][r]);
      }
    }
  }
}

__device__ __forceinline__ float lrelu(float x) { return x > 0.f ? x : NEG_SLOPE * x; }

// ---------------- segment softmax + aggregation: ONE WAVE PER NODE ----------------
// Output: fp32 (outf), or bf16 hi/lo (outh+outl), or bf16 only (outh, outl=null).
__global__ __launch_bounds__(256) void aggregate_kernel(
    const ush* __restrict__ hbf, const float* __restrict__ asrc,
    const float* __restrict__ adst, const int* __restrict__ row_ptr,
    const int* __restrict__ srcs, const float* __restrict__ bias,
    float* __restrict__ outf, ush* __restrict__ outh, ush* __restrict__ outl, int N) {
  __shared__ float s_alpha[4][64 * 4];
  __shared__ int s_src[4][64];

  int wave = threadIdx.x >> 6;
  int lane = threadIdx.x & 63;
  int node = blockIdx.x * 4 + wave;
  if (node >= N) return;

  int begin = row_ptr[node];
  int end = row_ptr[node + 1];
  int deg = end - begin;
  int nb = deg < 64 ? deg : 64;

  const float4* asrc4 = (const float4*)asrc;
  float4 ad = ((const float4*)adst)[node];

  const float NEGINF = -3.402823466e38f;
  int s0 = 0;
  float4 e0 = make_float4(NEGINF, NEGINF, NEGINF, NEGINF);
  if (lane < nb) {
    s0 = srcs[begin + lane];
    float4 a = asrc4[s0];
    e0.x = lrelu(a.x + ad.x);
    e0.y = lrelu(a.y + ad.y);
    e0.z = lrelu(a.z + ad.z);
    e0.w = lrelu(a.w + ad.w);
  }
  float m0 = e0.x, m1 = e0.y, m2 = e0.z, m3 = e0.w;
  for (int base = 64; base < deg; base += 64) {
    int idx = base + lane;
    if (idx < deg) {
      int s = srcs[begin + idx];
      float4 a = asrc4[s];
      m0 = fmaxf(m0, lrelu(a.x + ad.x));
      m1 = fmaxf(m1, lrelu(a.y + ad.y));
      m2 = fmaxf(m2, lrelu(a.z + ad.z));
      m3 = fmaxf(m3, lrelu(a.w + ad.w));
    }
  }
#pragma unroll
  for (int o = 1; o < 64; o <<= 1) {
    m0 = fmaxf(m0, __shfl_xor(m0, o, 64));
    m1 = fmaxf(m1, __shfl_xor(m1, o, 64));
    m2 = fmaxf(m2, __shfl_xor(m2, o, 64));
    m3 = fmaxf(m3, __shfl_xor(m3, o, 64));
  }
  float ex0 = (lane < nb) ? __expf(e0.x - m0) : 0.f;
  float ex1 = (lane < nb) ? __expf(e0.y - m1) : 0.f;
  float ex2 = (lane < nb) ? __expf(e0.z - m2) : 0.f;
  float ex3 = (lane < nb) ? __expf(e0.w - m3) : 0.f;
  float d0 = ex0, d1 = ex1, d2 = ex2, d3 = ex3;
  for (int base = 64; base < deg; base += 64) {
    int idx = base + lane;
    if (idx < deg) {
      int s = srcs[begin + idx];
      float4 a = asrc4[s];
      d0 += __expf(lrelu(a.x + ad.x) - m0);
      d1 += __expf(lrelu(a.y + ad.y) - m1);
      d2 += __expf(lrelu(a.z + ad.z) - m2);
      d3 += __expf(lrelu(a.w + ad.w) - m3);
    }
  }
#pragma unroll
  for (int o = 1; o < 64; o <<= 1) {
    d0 += __shfl_xor(d0, o, 64);
    d1 += __shfl_xor(d1, o, 64);
    d2 += __shfl_xor(d2, o, 64);
    d3 += __shfl_xor(d3, o, 64);
  }
  float r0 = 1.0f / (d0 + 1e-16f);
  float r1 = 1.0f / (d1 + 1e-16f);
  float r2 = 1.0f / (d2 + 1e-16f);
  float r3 = 1.0f / (d3 + 1e-16f);

  *(float4*)&s_alpha[wave][lane * 4] = make_float4(ex0 * r0, ex1 * r1, ex2 * r2, ex3 * r3);
  s_src[wave][lane] = s0;

  int head = lane >> 4;
  float mh = (head == 0) ? m0 : (head == 1) ? m1 : (head == 2) ? m2 : m3;
  float rdh = (head == 0) ? r0 : (head == 1) ? r1 : (head == 2) ? r2 : r3;
  float adh = (head == 0) ? ad.x : (head == 1) ? ad.y : (head == 2) ? ad.z : ad.w;

  const ushort4* hb4 = (const ushort4*)hbf;
  float4 accA = make_float4(0.f, 0.f, 0.f, 0.f);
  float4 accB = accA, accC = accA, accD = accA;
  int i = 0;
  for (; i + 4 <= nb; i += 4) {
    int sa = s_src[wave][i];
    int sb = s_src[wave][i + 1];
    int sc = s_src[wave][i + 2];
    int sd = s_src[wave][i + 3];
    float aa = s_alpha[wave][i * 4 + head];
    float ab = s_alpha[wave][(i + 1) * 4 + head];
    float ac = s_alpha[wave][(i + 2) * 4 + head];
    float ad_ = s_alpha[wave][(i + 3) * 4 + head];
    ushort4 u0 = hb4[(size_t)sa * 64 + lane];
    ushort4 u1 = hb4[(size_t)sb * 64 + lane];
    ushort4 u2 = hb4[(size_t)sc * 64 + lane];
    ushort4 u3 = hb4[(size_t)sd * 64 + lane];
    accA.x += aa * bf2f(u0.x); accA.y += aa * bf2f(u0.y);
    accA.z += aa * bf2f(u0.z); accA.w += aa * bf2f(u0.w);
    accB.x += ab * bf2f(u1.x); accB.y += ab * bf2f(u1.y);
    accB.z += ab * bf2f(u1.z); accB.w += ab * bf2f(u1.w);
    accC.x += ac * bf2f(u2.x); accC.y += ac * bf2f(u2.y);
    accC.z += ac * bf2f(u2.z); accC.w += ac * bf2f(u2.w);
    accD.x += ad_ * bf2f(u3.x); accD.y += ad_ * bf2f(u3.y);
    accD.z += ad_ * bf2f(u3.z); accD.w += ad_ * bf2f(u3.w);
  }
  for (; i < nb; ++i) {
    int s = s_src[wave][i];
    float a = s_alpha[wave][i * 4 + head];
    ushort4 u = hb4[(size_t)s * 64 + lane];
    accA.x += a * bf2f(u.x); accA.y += a * bf2f(u.y);
    accA.z += a * bf2f(u.z); accA.w += a * bf2f(u.w);
  }
  for (int i2 = 64; i2 < deg; ++i2) {
    int s = srcs[begin + i2];
    float ash = asrc[s * HEADS + head];
    float a = __expf(lrelu(ash + adh) - mh) * rdh;
    ushort4 u = hb4[(size_t)s * 64 + lane];
    accA.x += a * bf2f(u.x); accA.y += a * bf2f(u.y);
    accA.z += a * bf2f(u.z); accA.w += a * bf2f(u.w);
  }

  float4 acc;
  acc.x = (accA.x + accB.x) + (accC.x + accD.x);
  acc.y = (accA.y + accB.y) + (accC.y + accD.y);
  acc.z = (accA.z + accB.z) + (accC.z + accD.z);
  acc.w = (accA.w + accB.w) + (accC.w + accD.w);
  float4 bv = ((const float4*)bias)[lane];
  float4 o;
  o.x = fmaxf(acc.x + bv.x, 0.f);
  o.y = fmaxf(acc.y + bv.y, 0.f);
  o.z = fmaxf(acc.z + bv.z, 0.f);
  o.w = fmaxf(acc.w + bv.w, 0.f);

  if (outf) {
    ((float4*)outf)[(size_t)node * 64 + lane] = o;
  } else {
    ushort4 h = make_ushort4(f2bf(o.x), f2bf(o.y), f2bf(o.z), f2bf(o.w));
    ((ushort4*)outh)[(size_t)node * 64 + lane] = h;
    if (outl) {
      ushort4 l = make_ushort4(f2bf(o.x - bf2f(h.x)), f2bf(o.y - bf2f(h.y)),
                               f2bf(o.z - bf2f(h.z)), f2bf(o.w - bf2f(h.w)));
      ((ushort4*)outl)[(size_t)node * 64 + lane] = l;
    }
  }
}

// ---------------- global mean pool (batch is sorted, input bf16), 4 partials per graph ----------------
__device__ __forceinline__ int lower_bound_i(const int* a, int n, int key) {
  int lo = 0, hi = n;
  while (lo < hi) {
    int mid = (lo + hi) >> 1;
    if (a[mid] < key) lo = mid + 1; else hi = mid;
  }
  return lo;
}

__global__ __launch_bounds__(256) void pool_kernel(const ush* __restrict__ h2,
                                                   const int* __restrict__ batch,
                                                   float* __restrict__ pws,
                                                   int* __restrict__ cnts, int n) {
  int g = blockIdx.x, part = blockIdx.y;
  int wave = threadIdx.x >> 6, lane = threadIdx.x & 63;
  int lo = lower_bound_i(batch, n, g);
  int hi = lower_bound_i(batch, n, g + 1);
  const ushort4* h4 = (const ushort4*)h2;
  float4 acc = make_float4(0.f, 0.f, 0.f, 0.f);
  for (int i = lo + part * 4 + wave; i < hi; i += 16) {
    ushort4 u = h4[(size_t)i * 64 + lane];
    acc.x += bf2f(u.x); acc.y += bf2f(u.y);
    acc.z += bf2f(u.z); acc.w += bf2f(u.w);
  }
  __shared__ float4 red[4][64];
  red[wave][lane] = acc;
  __syncthreads();
  if (wave == 0) {
    float4 a0 = red[0][lane], a1 = red[1][lane], a2 = red[2][lane], a3 = red[3][lane];
    float4 o;
    o.x = (a0.x + a1.x) + (a2.x + a3.x);
    o.y = (a0.y + a1.y) + (a2.y + a3.y);
    o.z = (a0.z + a1.z) + (a2.z + a3.z);
    o.w = (a0.w + a1.w) + (a2.w + a3.w);
    ((float4*)pws)[(size_t)(g * 4 + part) * 64 + lane] = o;
  }
  if (part == 0 && threadIdx.x == 0) cnts[g] = hi - lo;
}

// ---------------- combine partials + final linear [G,256]@[256,10] ----------------
__global__ void final_kernel(const float* __restrict__ pws, const int* __restrict__ cnts,
                             const float* __restrict__ Wf, const float* __restrict__ bf,
                             float* __restrict__ pooled_out, float* __restrict__ out) {
  int g = blockIdx.x, t = threadIdx.x;
  float s = pws[(size_t)(g * 4 + 0) * 256 + t] + pws[(size_t)(g * 4 + 1) * 256 + t] +
            pws[(size_t)(g * 4 + 2) * 256 + t] + pws[(size_t)(g * 4 + 3) * 256 + t];
  float inv = 1.0f / fmaxf((float)cnts[g], 1.0f);
  float pv = s * inv;
  pooled_out[g * HC + t] = pv;
  __shared__ float p[HC];
  p[t] = pv;
  __syncthreads();
  if (t < 10) {
    float acc = bf[t];
    for (int c = 0; c < HC; ++c) acc += p[c] * Wf[c * 10 + t];
    out[g * 10 + t] = acc;
  }
}

extern "C" void kernel_launch(void* const* d_in, const int* in_sizes, int n_in,
                              void* d_out, int out_size, void* d_ws, size_t ws_size,
                              hipStream_t stream) {
  const float* x    = (const float*)d_in[0];
  const int*   ei   = (const int*)d_in[1];
  const int*   batch = (const int*)d_in[3];
  const float* W1   = (const float*)d_in[4];
  const float* as1  = (const float*)d_in[5];
  const float* ad1  = (const float*)d_in[6];
  const float* b1   = (const float*)d_in[7];
  const float* W2   = (const float*)d_in[8];
  const float* as2  = (const float*)d_in[9];
  const float* ad2  = (const float*)d_in[10];
  const float* b2   = (const float*)d_in[11];
  const float* Wf   = (const float*)d_in[12];
  const float* bf   = (const float*)d_in[13];
  float* out = (float*)d_out;

  const int N = in_sizes[0] / HC;  // 50000
  const int E = in_sizes[1] / 2;   // 800000

  // workspace layout (256B-aligned chunks)
  char* base = (char*)d_ws;
  size_t off = 0;
  auto alloc = [&](size_t bytes) {
    char* p = base + off;
    off = (off + bytes + 255) & ~(size_t)255;
    return p;
  };
  ush* xh = (ush*)alloc((size_t)N * HC * 2);   // bf16 hi (A for gemm; reused for agg2 out)
  ush* xl = (ush*)alloc((size_t)N * HC * 2);   // bf16 lo
  ush* hbf = (ush*)alloc((size_t)N * HC * 2);  // bf16 projected features
  float* asrc = (float*)alloc((size_t)N * HEADS * 4);
  float* adst = (float*)alloc((size_t)N * HEADS * 4);
  int* counts = (int*)alloc((size_t)N * 4);
  int* row_ptr = (int*)alloc((size_t)(N + 1) * 4);
  int* cursor = (int*)alloc((size_t)N * 4);
  int* srcs = (int*)alloc((size_t)(E + N) * 4);
  int* bsums = (int*)alloc(((N + 1023) / 1024) * 4);
  ush* Bth1 = (ush*)alloc((size_t)HC * HC * 2);
  ush* Btl1 = (ush*)alloc((size_t)HC * HC * 2);
  ush* Bth2 = (ush*)alloc((size_t)HC * HC * 2);
  ush* Btl2 = (ush*)alloc((size_t)HC * HC * 2);
  float* pws = (float*)alloc((size_t)GG * 4 * HC * 4);
  int* cnts = (int*)alloc((size_t)GG * 4);

  int nb = (N + 1023) / 1024;

  // CSR build
  hipMemsetAsync(counts, 0, (size_t)N * 4, stream);
  hist_kernel<<<(E + N + 255) / 256, 256, 0, stream>>>(ei, counts, E, N);
  scan_pass1<<<nb, 256, 0, stream>>>(counts, bsums, N);
  scan_pass2<<<1, 256, 0, stream>>>(bsums, row_ptr, nb, N);
  scan_pass3<<<nb, 256, 0, stream>>>(counts, bsums, row_ptr, cursor, N);
  scatter_kernel<<<(E + N + 255) / 256, 256, 0, stream>>>(ei, cursor, srcs, E, N);

  // weight prep + x split
  dim3 cbgrid(HC, 2);
  convertB_kernel<<<cbgrid, HC, 0, stream>>>(W1, W2, Bth1, Btl1, Bth2, Btl2);
  splitA_kernel<<<(N * HC / 4 + 255) / 256, 256, 0, stream>>>(x, xh, xl, N * HC);

  int ggrid = (N + 127) / 128;
  int agg_blocks = (N + 3) / 4;

  // layer 1 (aggregate emits bf16 hi/lo for layer-2 GEMM)
  gemm_kernel<<<ggrid, 256, 0, stream>>>(xh, xl, Bth1, Btl1, as1, ad1, hbf, asrc, adst, N);
  aggregate_kernel<<<agg_blocks, 256, 0, stream>>>(hbf, asrc, adst, row_ptr, srcs, b1,
                                                   nullptr, xh, xl, N);

  // layer 2 (aggregate emits bf16 for pooling; write into xh, free after gemm2)
  gemm_kernel<<<ggrid, 256, 0, stream>>>(xh, xl, Bth2, Btl2, as2, ad2, hbf, asrc, adst, N);
  aggregate_kernel<<<agg_blocks, 256, 0, stream>>>(hbf, asrc, adst, row_ptr, srcs, b2,
                                                   nullptr, xh, nullptr, N);

  // pooling + classifier
  dim3 pgrid(GG, 4);
  pool_kernel<<<pgrid, 256, 0, stream>>>(xh, batch, pws, cnts, N);
  final_kernel<<<GG, 256, 0, stream>>>(pws, cnts, Wf, bf, out + GG * 10, out);
}

// Round 8
// 471.786 us; speedup vs baseline: 1.0829x; 1.0829x over previous
//
#include <hip/hip_runtime.h>
#include <math.h>

#define HEADS 4
#define HID 64
#define HC 256
#define NEG_SLOPE 0.2f
#define GG 128

typedef __attribute__((ext_vector_type(8))) short short8;
typedef __attribute__((ext_vector_type(4))) float floatx4;
typedef unsigned short ush;

__device__ __forceinline__ ush f2bf(float f) {
  unsigned u = __float_as_uint(f);
  unsigned r = (u + 0x7FFFu + ((u >> 16) & 1u)) >> 16;  // RNE
  return (ush)r;
}
__device__ __forceinline__ float bf2f(ush h) {
  return __uint_as_float(((unsigned)h) << 16);
}

// ---------------- CSR build (counting sort by dst) ----------------
__global__ void hist_kernel(const int* __restrict__ ei, int* counts, int E, int n) {
  int i = blockIdx.x * 256 + threadIdx.x;
  if (i >= E + n) return;
  int d = (i < E) ? ei[E + i] : (i - E);
  atomicAdd(&counts[d], 1);
}

__global__ __launch_bounds__(256) void scan_pass1(const int* __restrict__ counts,
                                                  int* __restrict__ bsums, int n) {
  int t = threadIdx.x;
  int i0 = blockIdx.x * 1024 + t * 4;
  int s = 0;
  if (i0 + 3 < n) {
    int4 v = *(const int4*)&counts[i0];
    s = v.x + v.y + v.z + v.w;
  } else {
#pragma unroll
    for (int k = 0; k < 4; ++k)
      if (i0 + k < n) s += counts[i0 + k];
  }
#pragma unroll
  for (int o = 1; o < 64; o <<= 1) s += __shfl_xor(s, o, 64);
  __shared__ int ws[4];
  if ((t & 63) == 0) ws[t >> 6] = s;
  __syncthreads();
  if (t == 0) bsums[blockIdx.x] = ws[0] + ws[1] + ws[2] + ws[3];
}

__global__ __launch_bounds__(256) void scan_pass2(int* __restrict__ bsums,
                                                  int* __restrict__ row_ptr, int nb, int n) {
  __shared__ int sh[256];
  int t = threadIdx.x;
  int v = (t < nb) ? bsums[t] : 0;
  sh[t] = v;
  __syncthreads();
  for (int off = 1; off < 256; off <<= 1) {
    int u = (t >= off) ? sh[t - off] : 0;
    __syncthreads();
    sh[t] += u;
    __syncthreads();
  }
  if (t < nb) bsums[t] = sh[t] - v;  // exclusive
  if (t == 255) row_ptr[n] = sh[255];
}

__global__ __launch_bounds__(256) void scan_pass3(const int* __restrict__ counts,
                                                  const int* __restrict__ bsums,
                                                  int* __restrict__ row_ptr,
                                                  int* __restrict__ cursor, int n) {
  int t = threadIdx.x;
  int i0 = blockIdx.x * 1024 + t * 4;
  int c0 = 0, c1 = 0, c2 = 0, c3 = 0;
  bool full = (i0 + 3 < n);
  if (full) {
    int4 v = *(const int4*)&counts[i0];
    c0 = v.x; c1 = v.y; c2 = v.z; c3 = v.w;
  } else {
    if (i0 + 0 < n) c0 = counts[i0 + 0];
    if (i0 + 1 < n) c1 = counts[i0 + 1];
    if (i0 + 2 < n) c2 = counts[i0 + 2];
    if (i0 + 3 < n) c3 = counts[i0 + 3];
  }
  int ts = c0 + c1 + c2 + c3;
  __shared__ int sh[256];
  sh[t] = ts;
  __syncthreads();
  for (int off = 1; off < 256; off <<= 1) {
    int u = (t >= off) ? sh[t - off] : 0;
    __syncthreads();
    sh[t] += u;
    __syncthreads();
  }
  int run = bsums[blockIdx.x] + sh[t] - ts;
  int r0 = run, r1 = run + c0, r2 = r1 + c1, r3 = r2 + c2;
  if (full) {
    *(int4*)&row_ptr[i0] = make_int4(r0, r1, r2, r3);
    *(int4*)&cursor[i0] = make_int4(r0, r1, r2, r3);
  } else {
    if (i0 + 0 < n) { row_ptr[i0 + 0] = r0; cursor[i0 + 0] = r0; }
    if (i0 + 1 < n) { row_ptr[i0 + 1] = r1; cursor[i0 + 1] = r1; }
    if (i0 + 2 < n) { row_ptr[i0 + 2] = r2; cursor[i0 + 2] = r2; }
    if (i0 + 3 < n) { row_ptr[i0 + 3] = r3; cursor[i0 + 3] = r3; }
  }
}

__global__ void scatter_kernel(const int* __restrict__ ei, int* cursor, int* srcs, int E, int n) {
  int i = blockIdx.x * 256 + threadIdx.x;
  if (i >= E + n) return;
  int s, d;
  if (i < E) { s = ei[i]; d = ei[E + i]; }
  else       { s = i - E; d = s; }
  int pos = atomicAdd(&cursor[d], 1);
  srcs[pos] = s;
}

// ---------------- fp32 -> bf16 hi/lo split (elementwise) ----------------
__global__ __launch_bounds__(256) void splitA_kernel(const float* __restrict__ A,
                                                     ush* __restrict__ Ah,
                                                     ush* __restrict__ Al, int total) {
  int i0 = (blockIdx.x * 256 + threadIdx.x) * 4;
  if (i0 + 3 < total) {
    float4 v = *(const float4*)&A[i0];
    ushort4 h = make_ushort4(f2bf(v.x), f2bf(v.y), f2bf(v.z), f2bf(v.w));
    ushort4 l = make_ushort4(f2bf(v.x - bf2f(h.x)), f2bf(v.y - bf2f(h.y)),
                             f2bf(v.z - bf2f(h.z)), f2bf(v.w - bf2f(h.w)));
    *(ushort4*)&Ah[i0] = h;
    *(ushort4*)&Al[i0] = l;
  } else {
    for (int k = 0; k < 4 && i0 + k < total; ++k) {
      float v = A[i0 + k];
      ush h = f2bf(v);
      Ah[i0 + k] = h;
      Al[i0 + k] = f2bf(v - bf2f(h));
    }
  }
}

// ---------------- both B matrices: fp32 [256,256] -> bf16 hi/lo TRANSPOSED [n][k] ----------------
__global__ void convertB_kernel(const float* __restrict__ W1, const float* __restrict__ W2,
                                ush* __restrict__ Bth1, ush* __restrict__ Btl1,
                                ush* __restrict__ Bth2, ush* __restrict__ Btl2) {
  int k = blockIdx.x, n = threadIdx.x;
  const float* B = blockIdx.y ? W2 : W1;
  ush* th = blockIdx.y ? Bth2 : Bth1;
  ush* tl = blockIdx.y ? Btl2 : Btl1;
  float v = B[k * HC + n];
  ush h = f2bf(v);
  ush l = f2bf(v - bf2f(h));
  th[n * HC + k] = h;
  tl[n * HC + k] = l;
}

// ---------------- bf16-split MFMA GEMM (128x128, reg-prefetched K-loop) ----------------
// grid (2, ceil(M/128)), block 256 (4 waves, 2x2 of 64x64)
#define LDA 40  // padded k-stride in shorts (80B)
__global__ __launch_bounds__(256) void gemm_kernel(
    const ush* __restrict__ Ah, const ush* __restrict__ Al,
    const ush* __restrict__ Bth, const ush* __restrict__ Btl,
    const float* __restrict__ att_src, const float* __restrict__ att_dst,
    ush* __restrict__ Cb, float* __restrict__ asrc_o, float* __restrict__ adst_o, int M) {
  __shared__ ush sAh[128 * LDA];
  __shared__ ush sAl[128 * LDA];
  __shared__ ush sBh[128 * LDA];
  __shared__ ush sBl[128 * LDA];

  int t = threadIdx.x;
  int lane = t & 63, wave = t >> 6;
  int wm = wave >> 1, wn = wave & 1;
  int q = lane >> 4, mrow = lane & 15;
  int r0 = blockIdx.y * 128;
  int c0 = blockIdx.x * 128;
  const int4 zero4 = make_int4(0, 0, 0, 0);

  // staging tasks: 512 (row,seg8) pairs per array -> thread does t and t+256
  int row0 = t >> 2, seg0 = t & 3;
  int row1 = (t + 256) >> 2, seg1 = (t + 256) & 3;
  bool v0 = (r0 + row0) < M, v1 = (r0 + row1) < M;

  const ush* Ag0 = Ah + (size_t)(r0 + row0) * HC + seg0 * 8;
  const ush* Ag1 = Ah + (size_t)(r0 + row1) * HC + seg1 * 8;
  const ush* Al0 = Al + (size_t)(r0 + row0) * HC + seg0 * 8;
  const ush* Al1 = Al + (size_t)(r0 + row1) * HC + seg1 * 8;
  const ush* Bg0 = Bth + (size_t)(c0 + row0) * HC + seg0 * 8;
  const ush* Bg1 = Bth + (size_t)(c0 + row1) * HC + seg1 * 8;
  const ush* Bl0 = Btl + (size_t)(c0 + row0) * HC + seg0 * 8;
  const ush* Bl1 = Btl + (size_t)(c0 + row1) * HC + seg1 * 8;

  int4 pAh0, pAh1, pAl0, pAl1, pBh0, pBh1, pBl0, pBl1;
  // prefetch k0 = 0
  pAh0 = v0 ? *(const int4*)(Ag0) : zero4;
  pAh1 = v1 ? *(const int4*)(Ag1) : zero4;
  pAl0 = v0 ? *(const int4*)(Al0) : zero4;
  pAl1 = v1 ? *(const int4*)(Al1) : zero4;
  pBh0 = *(const int4*)(Bg0);
  pBh1 = *(const int4*)(Bg1);
  pBl0 = *(const int4*)(Bl0);
  pBl1 = *(const int4*)(Bl1);

  floatx4 acc[4][4];
#pragma unroll
  for (int i = 0; i < 4; ++i)
#pragma unroll
    for (int j = 0; j < 4; ++j) acc[i][j] = (floatx4)(0.0f);

  for (int k0 = 0; k0 < HC; k0 += 32) {
    // write prefetched tile to LDS
    *(int4*)&sAh[row0 * LDA + seg0 * 8] = pAh0;
    *(int4*)&sAh[row1 * LDA + seg1 * 8] = pAh1;
    *(int4*)&sAl[row0 * LDA + seg0 * 8] = pAl0;
    *(int4*)&sAl[row1 * LDA + seg1 * 8] = pAl1;
    *(int4*)&sBh[row0 * LDA + seg0 * 8] = pBh0;
    *(int4*)&sBh[row1 * LDA + seg1 * 8] = pBh1;
    *(int4*)&sBl[row0 * LDA + seg0 * 8] = pBl0;
    *(int4*)&sBl[row1 * LDA + seg1 * 8] = pBl1;
    __syncthreads();

    // issue next iteration's global loads (latency overlaps MFMA phase)
    int kn = k0 + 32;
    if (kn < HC) {
      pAh0 = v0 ? *(const int4*)(Ag0 + kn) : zero4;
      pAh1 = v1 ? *(const int4*)(Ag1 + kn) : zero4;
      pAl0 = v0 ? *(const int4*)(Al0 + kn) : zero4;
      pAl1 = v1 ? *(const int4*)(Al1 + kn) : zero4;
      pBh0 = *(const int4*)(Bg0 + kn);
      pBh1 = *(const int4*)(Bg1 + kn);
      pBl0 = *(const int4*)(Bl0 + kn);
      pBl1 = *(const int4*)(Bl1 + kn);
    }

    short8 ah[4], al[4], bh[4], bl[4];
#pragma unroll
    for (int i = 0; i < 4; ++i) {
      int ar = (wm * 64 + i * 16 + mrow) * LDA + q * 8;
      int br = (wn * 64 + i * 16 + mrow) * LDA + q * 8;
      ah[i] = *(short8*)&sAh[ar];
      al[i] = *(short8*)&sAl[ar];
      bh[i] = *(short8*)&sBh[br];
      bl[i] = *(short8*)&sBl[br];
    }
#pragma unroll
    for (int i = 0; i < 4; ++i)
#pragma unroll
      for (int j = 0; j < 4; ++j) {
        acc[i][j] = __builtin_amdgcn_mfma_f32_16x16x32_bf16(ah[i], bh[j], acc[i][j], 0, 0, 0);
        acc[i][j] = __builtin_amdgcn_mfma_f32_16x16x32_bf16(ah[i], bl[j], acc[i][j], 0, 0, 0);
        acc[i][j] = __builtin_amdgcn_mfma_f32_16x16x32_bf16(al[i], bh[j], acc[i][j], 0, 0, 0);
      }
    __syncthreads();
  }

  // ---- fused att: wave wn owns head hd's full 64-col stripe ----
  int hd = (c0 >> 6) + wn;
  float aS[4], aD[4];
#pragma unroll
  for (int j = 0; j < 4; ++j) {
    aS[j] = att_src[hd * 64 + j * 16 + mrow];
    aD[j] = att_dst[hd * 64 + j * 16 + mrow];
  }
#pragma unroll
  for (int i = 0; i < 4; ++i) {
#pragma unroll
    for (int r = 0; r < 4; ++r) {
      float ps = acc[i][0][r] * aS[0] + acc[i][1][r] * aS[1] +
                 acc[i][2][r] * aS[2] + acc[i][3][r] * aS[3];
      float pd = acc[i][0][r] * aD[0] + acc[i][1][r] * aD[1] +
                 acc[i][2][r] * aD[2] + acc[i][3][r] * aD[3];
#pragma unroll
      for (int o = 1; o < 16; o <<= 1) {
        ps += __shfl_xor(ps, o, 64);
        pd += __shfl_xor(pd, o, 64);
      }
      int grow = r0 + wm * 64 + i * 16 + q * 4 + r;
      if (mrow == 0 && grow < M) {
        asrc_o[grow * HEADS + hd] = ps;
        adst_o[grow * HEADS + hd] = pd;
      }
    }
  }

  // ---- bf16 C store (C/D layout: col=lane&15, row=(lane>>4)*4+reg) ----
#pragma unroll
  for (int i = 0; i < 4; ++i) {
#pragma unroll
    for (int j = 0; j < 4; ++j) {
      int col = c0 + wn * 64 + j * 16 + mrow;
#pragma unroll
      for (int r = 0; r < 4; ++r) {
        int grow = r0 + wm * 64 + i * 16 + q * 4 + r;
        if (grow < M) Cb[(size_t)grow * HC + col] = f2bf(acc[i][j][r]);
      }
    }
  }
}

__device__ __forceinline__ float lrelu(float x) { return x > 0.f ? x : NEG_SLOPE * x; }

// ---------------- segment softmax + aggregation: ONE WAVE PER NODE ----------------
__global__ __launch_bounds__(256) void aggregate_kernel(
    const ush* __restrict__ hbf, const float* __restrict__ asrc,
    const float* __restrict__ adst, const int* __restrict__ row_ptr,
    const int* __restrict__ srcs, const float* __restrict__ bias,
    float* __restrict__ outf, ush* __restrict__ outh, ush* __restrict__ outl, int N) {
  __shared__ float s_alpha[4][64 * 4];
  __shared__ int s_src[4][64];

  int wave = threadIdx.x >> 6;
  int lane = threadIdx.x & 63;
  int node = blockIdx.x * 4 + wave;
  if (node >= N) return;

  int begin = row_ptr[node];
  int end = row_ptr[node + 1];
  int deg = end - begin;
  int nb = deg < 64 ? deg : 64;

  const float4* asrc4 = (const float4*)asrc;
  float4 ad = ((const float4*)adst)[node];

  const float NEGINF = -3.402823466e38f;
  int s0 = 0;
  float4 e0 = make_float4(NEGINF, NEGINF, NEGINF, NEGINF);
  if (lane < nb) {
    s0 = srcs[begin + lane];
    float4 a = asrc4[s0];
    e0.x = lrelu(a.x + ad.x);
    e0.y = lrelu(a.y + ad.y);
    e0.z = lrelu(a.z + ad.z);
    e0.w = lrelu(a.w + ad.w);
  }
  float m0 = e0.x, m1 = e0.y, m2 = e0.z, m3 = e0.w;
  for (int base = 64; base < deg; base += 64) {
    int idx = base + lane;
    if (idx < deg) {
      int s = srcs[begin + idx];
      float4 a = asrc4[s];
      m0 = fmaxf(m0, lrelu(a.x + ad.x));
      m1 = fmaxf(m1, lrelu(a.y + ad.y));
      m2 = fmaxf(m2, lrelu(a.z + ad.z));
      m3 = fmaxf(m3, lrelu(a.w + ad.w));
    }
  }
#pragma unroll
  for (int o = 1; o < 64; o <<= 1) {
    m0 = fmaxf(m0, __shfl_xor(m0, o, 64));
    m1 = fmaxf(m1, __shfl_xor(m1, o, 64));
    m2 = fmaxf(m2, __shfl_xor(m2, o, 64));
    m3 = fmaxf(m3, __shfl_xor(m3, o, 64));
  }
  float ex0 = (lane < nb) ? __expf(e0.x - m0) : 0.f;
  float ex1 = (lane < nb) ? __expf(e0.y - m1) : 0.f;
  float ex2 = (lane < nb) ? __expf(e0.z - m2) : 0.f;
  float ex3 = (lane < nb) ? __expf(e0.w - m3) : 0.f;
  float d0 = ex0, d1 = ex1, d2 = ex2, d3 = ex3;
  for (int base = 64; base < deg; base += 64) {
    int idx = base + lane;
    if (idx < deg) {
      int s = srcs[begin + idx];
      float4 a = asrc4[s];
      d0 += __expf(lrelu(a.x + ad.x) - m0);
      d1 += __expf(lrelu(a.y + ad.y) - m1);
      d2 += __expf(lrelu(a.z + ad.z) - m2);
      d3 += __expf(lrelu(a.w + ad.w) - m3);
    }
  }
#pragma unroll
  for (int o = 1; o < 64; o <<= 1) {
    d0 += __shfl_xor(d0, o, 64);
    d1 += __shfl_xor(d1, o, 64);
    d2 += __shfl_xor(d2, o, 64);
    d3 += __shfl_xor(d3, o, 64);
  }
  float r0 = 1.0f / (d0 + 1e-16f);
  float r1 = 1.0f / (d1 + 1e-16f);
  float r2 = 1.0f / (d2 + 1e-16f);
  float r3 = 1.0f / (d3 + 1e-16f);

  *(float4*)&s_alpha[wave][lane * 4] = make_float4(ex0 * r0, ex1 * r1, ex2 * r2, ex3 * r3);
  s_src[wave][lane] = s0;

  int head = lane >> 4;
  float mh = (head == 0) ? m0 : (head == 1) ? m1 : (head == 2) ? m2 : m3;
  float rdh = (head == 0) ? r0 : (head == 1) ? r1 : (head == 2) ? r2 : r3;
  float adh = (head == 0) ? ad.x : (head == 1) ? ad.y : (head == 2) ? ad.z : ad.w;

  const ushort4* hb4 = (const ushort4*)hbf;
  float4 accA = make_float4(0.f, 0.f, 0.f, 0.f);
  float4 accB = accA, accC = accA, accD = accA;
  int i = 0;
  for (; i + 4 <= nb; i += 4) {
    int sa = s_src[wave][i];
    int sb = s_src[wave][i + 1];
    int sc = s_src[wave][i + 2];
    int sd = s_src[wave][i + 3];
    float aa = s_alpha[wave][i * 4 + head];
    float ab = s_alpha[wave][(i + 1) * 4 + head];
    float ac = s_alpha[wave][(i + 2) * 4 + head];
    float ad_ = s_alpha[wave][(i + 3) * 4 + head];
    ushort4 u0 = hb4[(size_t)sa * 64 + lane];
    ushort4 u1 = hb4[(size_t)sb * 64 + lane];
    ushort4 u2 = hb4[(size_t)sc * 64 + lane];
    ushort4 u3 = hb4[(size_t)sd * 64 + lane];
    accA.x += aa * bf2f(u0.x); accA.y += aa * bf2f(u0.y);
    accA.z += aa * bf2f(u0.z); accA.w += aa * bf2f(u0.w);
    accB.x += ab * bf2f(u1.x); accB.y += ab * bf2f(u1.y);
    accB.z += ab * bf2f(u1.z); accB.w += ab * bf2f(u1.w);
    accC.x += ac * bf2f(u2.x); accC.y += ac * bf2f(u2.y);
    accC.z += ac * bf2f(u2.z); accC.w += ac * bf2f(u2.w);
    accD.x += ad_ * bf2f(u3.x); accD.y += ad_ * bf2f(u3.y);
    accD.z += ad_ * bf2f(u3.z); accD.w += ad_ * bf2f(u3.w);
  }
  for (; i < nb; ++i) {
    int s = s_src[wave][i];
    float a = s_alpha[wave][i * 4 + head];
    ushort4 u = hb4[(size_t)s * 64 + lane];
    accA.x += a * bf2f(u.x); accA.y += a * bf2f(u.y);
    accA.z += a * bf2f(u.z); accA.w += a * bf2f(u.w);
  }
  for (int i2 = 64; i2 < deg; ++i2) {
    int s = srcs[begin + i2];
    float ash = asrc[s * HEADS + head];
    float a = __expf(lrelu(ash + adh) - mh) * rdh;
    ushort4 u = hb4[(size_t)s * 64 + lane];
    accA.x += a * bf2f(u.x); accA.y += a * bf2f(u.y);
    accA.z += a * bf2f(u.z); accA.w += a * bf2f(u.w);
  }

  float4 acc;
  acc.x = (accA.x + accB.x) + (accC.x + accD.x);
  acc.y = (accA.y + accB.y) + (accC.y + accD.y);
  acc.z = (accA.z + accB.z) + (accC.z + accD.z);
  acc.w = (accA.w + accB.w) + (accC.w + accD.w);
  float4 bv = ((const float4*)bias)[lane];
  float4 o;
  o.x = fmaxf(acc.x + bv.x, 0.f);
  o.y = fmaxf(acc.y + bv.y, 0.f);
  o.z = fmaxf(acc.z + bv.z, 0.f);
  o.w = fmaxf(acc.w + bv.w, 0.f);

  if (outf) {
    ((float4*)outf)[(size_t)node * 64 + lane] = o;
  } else {
    ushort4 h = make_ushort4(f2bf(o.x), f2bf(o.y), f2bf(o.z), f2bf(o.w));
    ((ushort4*)outh)[(size_t)node * 64 + lane] = h;
    if (outl) {
      ushort4 l = make_ushort4(f2bf(o.x - bf2f(h.x)), f2bf(o.y - bf2f(h.y)),
                               f2bf(o.z - bf2f(h.z)), f2bf(o.w - bf2f(h.w)));
      ((ushort4*)outl)[(size_t)node * 64 + lane] = l;
    }
  }
}

// ---------------- global mean pool (batch is sorted, input bf16), 4 partials per graph ----------------
__device__ __forceinline__ int lower_bound_i(const int* a, int n, int key) {
  int lo = 0, hi = n;
  while (lo < hi) {
    int mid = (lo + hi) >> 1;
    if (a[mid] < key) lo = mid + 1; else hi = mid;
  }
  return lo;
}

__global__ __launch_bounds__(256) void pool_kernel(const ush* __restrict__ h2,
                                                   const int* __restrict__ batch,
                                                   float* __restrict__ pws,
                                                   int* __restrict__ cnts, int n) {
  int g = blockIdx.x, part = blockIdx.y;
  int wave = threadIdx.x >> 6, lane = threadIdx.x & 63;
  int lo = lower_bound_i(batch, n, g);
  int hi = lower_bound_i(batch, n, g + 1);
  const ushort4* h4 = (const ushort4*)h2;
  float4 acc = make_float4(0.f, 0.f, 0.f, 0.f);
  for (int i = lo + part * 4 + wave; i < hi; i += 16) {
    ushort4 u = h4[(size_t)i * 64 + lane];
    acc.x += bf2f(u.x); acc.y += bf2f(u.y);
    acc.z += bf2f(u.z); acc.w += bf2f(u.w);
  }
  __shared__ float4 red[4][64];
  red[wave][lane] = acc;
  __syncthreads();
  if (wave == 0) {
    float4 a0 = red[0][lane], a1 = red[1][lane], a2 = red[2][lane], a3 = red[3][lane];
    float4 o;
    o.x = (a0.x + a1.x) + (a2.x + a3.x);
    o.y = (a0.y + a1.y) + (a2.y + a3.y);
    o.z = (a0.z + a1.z) + (a2.z + a3.z);
    o.w = (a0.w + a1.w) + (a2.w + a3.w);
    ((float4*)pws)[(size_t)(g * 4 + part) * 64 + lane] = o;
  }
  if (part == 0 && threadIdx.x == 0) cnts[g] = hi - lo;
}

// ---------------- combine partials + final linear [G,256]@[256,10] ----------------
__global__ void final_kernel(const float* __restrict__ pws, const int* __restrict__ cnts,
                             const float* __restrict__ Wf, const float* __restrict__ bf,
                             float* __restrict__ pooled_out, float* __restrict__ out) {
  int g = blockIdx.x, t = threadIdx.x;
  float s = pws[(size_t)(g * 4 + 0) * 256 + t] + pws[(size_t)(g * 4 + 1) * 256 + t] +
            pws[(size_t)(g * 4 + 2) * 256 + t] + pws[(size_t)(g * 4 + 3) * 256 + t];
  float inv = 1.0f / fmaxf((float)cnts[g], 1.0f);
  float pv = s * inv;
  pooled_out[g * HC + t] = pv;
  __shared__ float p[HC];
  p[t] = pv;
  __syncthreads();
  if (t < 10) {
    float acc = bf[t];
    for (int c = 0; c < HC; ++c) acc += p[c] * Wf[c * 10 + t];
    out[g * 10 + t] = acc;
  }
}

extern "C" void kernel_launch(void* const* d_in, const int* in_sizes, int n_in,
                              void* d_out, int out_size, void* d_ws, size_t ws_size,
                              hipStream_t stream) {
  const float* x    = (const float*)d_in[0];
  const int*   ei   = (const int*)d_in[1];
  const int*   batch = (const int*)d_in[3];
  const float* W1   = (const float*)d_in[4];
  const float* as1  = (const float*)d_in[5];
  const float* ad1  = (const float*)d_in[6];
  const float* b1   = (const float*)d_in[7];
  const float* W2   = (const float*)d_in[8];
  const float* as2  = (const float*)d_in[9];
  const float* ad2  = (const float*)d_in[10];
  const float* b2   = (const float*)d_in[11];
  const float* Wf   = (const float*)d_in[12];
  const float* bf   = (const float*)d_in[13];
  float* out = (float*)d_out;

  const int N = in_sizes[0] / HC;  // 50000
  const int E = in_sizes[1] / 2;   // 800000

  // workspace layout (256B-aligned chunks)
  char* base = (char*)d_ws;
  size_t off = 0;
  auto alloc = [&](size_t bytes) {
    char* p = base + off;
    off = (off + bytes + 255) & ~(size_t)255;
    return p;
  };
  ush* xh = (ush*)alloc((size_t)N * HC * 2);   // bf16 hi (A for gemm; reused for agg out)
  ush* xl = (ush*)alloc((size_t)N * HC * 2);   // bf16 lo
  ush* hbf = (ush*)alloc((size_t)N * HC * 2);  // bf16 projected features
  float* asrc = (float*)alloc((size_t)N * HEADS * 4);
  float* adst = (float*)alloc((size_t)N * HEADS * 4);
  int* counts = (int*)alloc((size_t)N * 4);
  int* row_ptr = (int*)alloc((size_t)(N + 1) * 4);
  int* cursor = (int*)alloc((size_t)N * 4);
  int* srcs = (int*)alloc((size_t)(E + N) * 4);
  int* bsums = (int*)alloc(((N + 1023) / 1024) * 4);
  ush* Bth1 = (ush*)alloc((size_t)HC * HC * 2);
  ush* Btl1 = (ush*)alloc((size_t)HC * HC * 2);
  ush* Bth2 = (ush*)alloc((size_t)HC * HC * 2);
  ush* Btl2 = (ush*)alloc((size_t)HC * HC * 2);
  float* pws = (float*)alloc((size_t)GG * 4 * HC * 4);
  int* cnts = (int*)alloc((size_t)GG * 4);

  int nb = (N + 1023) / 1024;

  // CSR build
  hipMemsetAsync(counts, 0, (size_t)N * 4, stream);
  hist_kernel<<<(E + N + 255) / 256, 256, 0, stream>>>(ei, counts, E, N);
  scan_pass1<<<nb, 256, 0, stream>>>(counts, bsums, N);
  scan_pass2<<<1, 256, 0, stream>>>(bsums, row_ptr, nb, N);
  scan_pass3<<<nb, 256, 0, stream>>>(counts, bsums, row_ptr, cursor, N);
  scatter_kernel<<<(E + N + 255) / 256, 256, 0, stream>>>(ei, cursor, srcs, E, N);

  // weight prep + x split
  dim3 cbgrid(HC, 2);
  convertB_kernel<<<cbgrid, HC, 0, stream>>>(W1, W2, Bth1, Btl1, Bth2, Btl2);
  splitA_kernel<<<(N * HC / 4 + 255) / 256, 256, 0, stream>>>(x, xh, xl, N * HC);

  dim3 ggrid(2, (N + 127) / 128);
  int agg_blocks = (N + 3) / 4;

  // layer 1 (aggregate emits bf16 hi/lo for layer-2 GEMM)
  gemm_kernel<<<ggrid, 256, 0, stream>>>(xh, xl, Bth1, Btl1, as1, ad1, hbf, asrc, adst, N);
  aggregate_kernel<<<agg_blocks, 256, 0, stream>>>(hbf, asrc, adst, row_ptr, srcs, b1,
                                                   nullptr, xh, xl, N);

  // layer 2 (aggregate emits bf16 for pooling)
  gemm_kernel<<<ggrid, 256, 0, stream>>>(xh, xl, Bth2, Btl2, as2, ad2, hbf, asrc, adst, N);
  aggregate_kernel<<<agg_blocks, 256, 0, stream>>>(hbf, asrc, adst, row_ptr, srcs, b2,
                                                   nullptr, xh, nullptr, N);

  // pooling + classifier
  dim3 pgrid(GG, 4);
  pool_kernel<<<pgrid, 256, 0, stream>>>(xh, batch, pws, cnts, N);
  final_kernel<<<GG, 256, 0, stream>>>(pws, cnts, Wf, bf, out + GG * 10, out);
}